// Round 2
// baseline (807.281 us; speedup 1.0000x reference)
//
#include <hip/hip_runtime.h>

#define B_ 2
#define S_ 2048
#define HID_ 2048
#define H_ 16
#define HKV_ 8
#define HD_ 128
#define NCH_ 7
#define RET_ 64
#define IST_ 448            // INPUT_START
#define KVL_ 2496           // KV_LEN
#define SCALE_ 0.08838834764831845f

typedef __attribute__((ext_vector_type(8))) short short8;
typedef __attribute__((ext_vector_type(4))) float f32x4;

static __device__ __forceinline__ unsigned short f2bf(float f) {
    unsigned u = __float_as_uint(f);
    unsigned r = (u + 0x7fffu + ((u >> 16) & 1u)) >> 16;
    return (unsigned short)r;
}
static __device__ __forceinline__ float bf2f(unsigned short x) {
    return __uint_as_float(((unsigned)x) << 16);
}

#define GLL16(gp, lp) __builtin_amdgcn_global_load_lds( \
    (__attribute__((address_space(1))) void*)(void*)(gp), \
    (__attribute__((address_space(3))) void*)(void*)(lp), 16, 0, 0)

// ---------------- elementwise f32 -> bf16 ----------------
__global__ __launch_bounds__(256) void cvt_f32_bf16(const float* __restrict__ x,
                                                    unsigned short* __restrict__ y, int n4) {
    int i = blockIdx.x * 256 + threadIdx.x;
    if (i >= n4) return;
    float4 v = ((const float4*)x)[i];
    ushort4 o;
    o.x = f2bf(v.x); o.y = f2bf(v.y); o.z = f2bf(v.z); o.w = f2bf(v.w);
    ((ushort4*)y)[i] = o;
}

// ---------------- W (K x N, f32) -> WT (N x K, bf16) ----------------
__global__ __launch_bounds__(256) void transpose_cvt(const float* __restrict__ W,
                                                     unsigned short* __restrict__ WT,
                                                     int K, int N) {
    __shared__ float t[32][33];
    const int k0 = blockIdx.x << 5, n0 = blockIdx.y << 5;
    const int tx = threadIdx.x, ty = threadIdx.y;
#pragma unroll
    for (int i = 0; i < 4; i++)
        t[ty + i * 8][tx] = W[(size_t)(k0 + ty + i * 8) * N + n0 + tx];
    __syncthreads();
#pragma unroll
    for (int i = 0; i < 4; i++)
        WT[(size_t)(n0 + ty + i * 8) * K + k0 + tx] = f2bf(t[tx][ty + i * 8]);
}

// ---------------- GEMM: C(MxN) = A(MxK,bf16) * BT(NxK,bf16)^T ----------------
static __device__ __forceinline__ void store_out(unsigned short* p, float v) { *p = f2bf(v); }
static __device__ __forceinline__ void store_out(float* p, float v) { *p = v; }

template <typename OT>
__global__ __launch_bounds__(256) void gemm_bt(const unsigned short* __restrict__ A,
                                               const unsigned short* __restrict__ BT,
                                               OT* __restrict__ C,
                                               int M, int N, int K) {
    __shared__ short As[4096];  // 128 x 32 bf16
    __shared__ short Bs[4096];
    const int tid = threadIdx.x;
    const int wid = tid >> 6, lane = tid & 63;
    const int lq = lane & 15, lk = lane >> 4;
    const int wr = wid >> 1, wc = wid & 1;
    const int bm = blockIdx.x, bn = blockIdx.y;
    f32x4 acc[4][4] = {};
    const int r0 = tid >> 2, kp0 = (tid & 3) * 8;
    const int c1 = tid + 256;
    const int r1 = c1 >> 2, kp1 = (c1 & 3) * 8;
    const size_t arow0 = (size_t)(bm * 128 + r0) * K;
    const size_t arow1 = (size_t)(bm * 128 + r1) * K;
    const size_t brow0 = (size_t)(bn * 128 + r0) * K;
    const size_t brow1 = (size_t)(bn * 128 + r1) * K;
    for (int k0 = 0; k0 < K; k0 += 32) {
        GLL16(A + arow0 + k0 + kp0, As + wid * 512);
        GLL16(A + arow1 + k0 + kp1, As + 2048 + wid * 512);
        GLL16(BT + brow0 + k0 + kp0, Bs + wid * 512);
        GLL16(BT + brow1 + k0 + kp1, Bs + 2048 + wid * 512);
        asm volatile("s_waitcnt vmcnt(0)" ::: "memory");
        __syncthreads();
        short8 af[4], bf[4];
#pragma unroll
        for (int i = 0; i < 4; i++)
            af[i] = *(const short8*)(As + (wr * 64 + i * 16 + lq) * 32 + lk * 8);
#pragma unroll
        for (int j = 0; j < 4; j++)
            bf[j] = *(const short8*)(Bs + (wc * 64 + j * 16 + lq) * 32 + lk * 8);
#pragma unroll
        for (int i = 0; i < 4; i++)
#pragma unroll
            for (int j = 0; j < 4; j++)
                acc[i][j] = __builtin_amdgcn_mfma_f32_16x16x32_bf16(af[i], bf[j], acc[i][j], 0, 0, 0);
        __syncthreads();
    }
#pragma unroll
    for (int i = 0; i < 4; i++)
#pragma unroll
        for (int j = 0; j < 4; j++)
#pragma unroll
            for (int r = 0; r < 4; r++) {
                size_t row = (size_t)bm * 128 + wr * 64 + i * 16 + lk * 4 + r;
                size_t col = (size_t)bn * 128 + wc * 64 + j * 16 + lq;
                store_out(&C[row * N + col], acc[i][j][r]);
            }
}

// ---------------- RoPE Q: qraw(B*S, H*HD) -> qatt(B,H,S,HD) ----------------
__global__ __launch_bounds__(256) void rope_q_kernel(const unsigned short* __restrict__ qraw,
                                                     const float* __restrict__ cosb,
                                                     const float* __restrict__ sinb,
                                                     unsigned short* __restrict__ qatt) {
    size_t idx = (size_t)blockIdx.x * 256 + threadIdx.x;  // B*S*H*64
    int d = idx & 63;
    int h = (idx >> 6) & 15;
    size_t bs = idx >> 10;
    size_t base = bs * 2048 + h * 128 + d;
    float x1 = bf2f(qraw[base]), x2 = bf2f(qraw[base + 64]);
    float c1 = cosb[bs * 128 + d], sn1 = sinb[bs * 128 + d];
    float c2 = cosb[bs * 128 + d + 64], sn2 = sinb[bs * 128 + d + 64];
    int b = (int)(bs >> 11), s = (int)(bs & 2047);
    size_t o = ((size_t)(b * H_ + h) * S_ + s) * HD_ + d;
    qatt[o] = f2bf(x1 * c1 - x2 * sn1);
    qatt[o + 64] = f2bf(x2 * c2 + x1 * sn2);
}

// ---------------- RoPE K: kraw(B*S, HKV*HD) -> kall(B,HKV,KVL,HD) at 448+s ----------------
__global__ __launch_bounds__(256) void rope_k_kernel(const unsigned short* __restrict__ kraw,
                                                     const float* __restrict__ cosb,
                                                     const float* __restrict__ sinb,
                                                     unsigned short* __restrict__ kall) {
    size_t idx = (size_t)blockIdx.x * 256 + threadIdx.x;  // B*S*HKV*64
    int d = idx & 63;
    int hk = (idx >> 6) & 7;
    size_t bs = idx >> 9;
    size_t base = bs * 1024 + hk * 128 + d;
    float x1 = bf2f(kraw[base]), x2 = bf2f(kraw[base + 64]);
    float c1 = cosb[bs * 128 + d], sn1 = sinb[bs * 128 + d];
    float c2 = cosb[bs * 128 + d + 64], sn2 = sinb[bs * 128 + d + 64];
    int b = (int)(bs >> 11), s = (int)(bs & 2047);
    size_t o = ((size_t)(b * HKV_ + hk) * KVL_ + IST_ + s) * HD_ + d;
    kall[o] = f2bf(x1 * c1 - x2 * sn1);
    kall[o + 64] = f2bf(x2 * c2 + x1 * sn2);
}

// ---------------- V self: vraw(B*S, HKV*HD) -> vt(B,HKV,HD,KVL) at col 448+s ----------------
__global__ void scatter_v_kernel(const unsigned short* __restrict__ vraw,
                                 unsigned short* __restrict__ vt) {
    __shared__ unsigned short t[32][33];
    const int bh = blockIdx.z;
    const int b = bh >> 3, hk = bh & 7;
    const int d0 = blockIdx.x << 5, s0 = blockIdx.y << 5;
    const int tx = threadIdx.x, ty = threadIdx.y;
#pragma unroll
    for (int i = 0; i < 4; i++)
        t[ty + i * 8][tx] = vraw[(size_t)(b * S_ + s0 + ty + i * 8) * 1024 + hk * 128 + d0 + tx];
    __syncthreads();
#pragma unroll
    for (int i = 0; i < 4; i++)
        vt[((size_t)(b * HKV_ + hk) * HD_ + d0 + ty + i * 8) * KVL_ + IST_ + s0 + tx] = t[tx][ty + i * 8];
}

// ---------------- retrieval K: (B*NCH, HKV, 64, 128) f32 -> kall[.., ch*64+r, d] ----------------
__global__ __launch_bounds__(256) void scatter_rk_kernel(const float* __restrict__ rk,
                                                         unsigned short* __restrict__ kall) {
    size_t idx = (size_t)blockIdx.x * 256 + threadIdx.x;  // 14*8*64*128
    int d = idx & 127;
    int r = (idx >> 7) & 63;
    int hk = (idx >> 13) & 7;
    int bc = (int)(idx >> 16);
    int b = bc / NCH_, ch = bc % NCH_;
    kall[((size_t)(b * HKV_ + hk) * KVL_ + ch * RET_ + r) * HD_ + d] = f2bf(rk[idx]);
}

// ---------------- retrieval V: -> vt[.., d, ch*64+r] (transpose) ----------------
__global__ void scatter_rv_kernel(const float* __restrict__ rv,
                                  unsigned short* __restrict__ vt) {
    __shared__ float t[32][33];
    const int z = blockIdx.z;
    const int bc = z >> 3, hk = z & 7;
    const int b = bc / NCH_, ch = bc % NCH_;
    const int d0 = blockIdx.x << 5, r0 = blockIdx.y << 5;
    const int tx = threadIdx.x, ty = threadIdx.y;
#pragma unroll
    for (int i = 0; i < 4; i++)
        t[ty + i * 8][tx] = rv[((size_t)(bc * HKV_ + hk) * RET_ + r0 + ty + i * 8) * HD_ + d0 + tx];
    __syncthreads();
#pragma unroll
    for (int i = 0; i < 4; i++)
        vt[((size_t)(b * HKV_ + hk) * HD_ + d0 + ty + i * 8) * KVL_ + ch * RET_ + r0 + tx] =
            f2bf(t[tx][ty + i * 8]);
}

// ---------------- flash attention ----------------
// grid (S/64, H, B), 256 threads = 4 waves, 16 q-rows per wave
// NOTE: reference reshapes (B,H,S,HD) -> (B,S,H*HD) WITHOUT transposing heads:
//   out row s' = h*128 + q/16, col j = (q%16)*128 + d
__global__ __launch_bounds__(256) void attn_kernel(const unsigned short* __restrict__ qatt,
                                                   const unsigned short* __restrict__ kall,
                                                   const unsigned short* __restrict__ vt,
                                                   unsigned short* __restrict__ attnb) {
    __shared__ short plds[4][16][32];
    const int wid = threadIdx.x >> 6, lane = threadIdx.x & 63;
    const int lq = lane & 15, lk = lane >> 4;
    const int qb = blockIdx.x * 64 + wid * 16;
    const int h = blockIdx.y, b = blockIdx.z, hk = h >> 1;
    const unsigned short* qptr = qatt + ((size_t)(b * H_ + h) * S_ + qb + lq) * HD_;
    short8 qf[4];
#pragma unroll
    for (int d = 0; d < 4; d++) qf[d] = *(const short8*)(qptr + d * 32 + lk * 8);
    const unsigned short* kbase = kall + (size_t)(b * HKV_ + hk) * KVL_ * HD_;
    const unsigned short* vbase = vt + (size_t)(b * HKV_ + hk) * HD_ * KVL_;
    f32x4 o[8] = {};
    float m[4] = {-3e38f, -3e38f, -3e38f, -3e38f};
    float lsum[4] = {0.f, 0.f, 0.f, 0.f};
    const int doc = qb >> 8;

    auto tile = [&](int kv0) {
        f32x4 sa0 = {}, sa1 = {};
#pragma unroll
        for (int d = 0; d < 4; d++) {
            short8 kf0 = *(const short8*)(kbase + (size_t)(kv0 + lq) * HD_ + d * 32 + lk * 8);
            short8 kf1 = *(const short8*)(kbase + (size_t)(kv0 + 16 + lq) * HD_ + d * 32 + lk * 8);
            sa0 = __builtin_amdgcn_mfma_f32_16x16x32_bf16(qf[d], kf0, sa0, 0, 0, 0);
            sa1 = __builtin_amdgcn_mfma_f32_16x16x32_bf16(qf[d], kf1, sa1, 0, 0, 0);
        }
        float p0[4], p1[4], alpha[4];
#pragma unroll
        for (int r = 0; r < 4; r++) {
            const int qg = qb + lk * 4 + r;
            const int kg0 = kv0 + lq, kg1 = kv0 + 16 + lq;
            bool v0 = (kg0 < IST_) ? (doc >= 1 && (kg0 >> 6) == doc - 1)
                                   : (kg0 > IST_ && kg0 <= qg + IST_);
            bool v1 = (kg1 < IST_) ? (doc >= 1 && (kg1 >> 6) == doc - 1)
                                   : (kg1 > IST_ && kg1 <= qg + IST_);
            float s0 = v0 ? sa0[r] * SCALE_ : -3e38f;
            float s1 = v1 ? sa1[r] * SCALE_ : -3e38f;
            float mx = fmaxf(s0, s1);
            mx = fmaxf(mx, __shfl_xor(mx, 1));
            mx = fmaxf(mx, __shfl_xor(mx, 2));
            mx = fmaxf(mx, __shfl_xor(mx, 4));
            mx = fmaxf(mx, __shfl_xor(mx, 8));
            float mn = fmaxf(m[r], mx);
            float e0 = v0 ? expf(s0 - mn) : 0.f;
            float e1 = v1 ? expf(s1 - mn) : 0.f;
            float rs = e0 + e1;
            rs += __shfl_xor(rs, 1);
            rs += __shfl_xor(rs, 2);
            rs += __shfl_xor(rs, 4);
            rs += __shfl_xor(rs, 8);
            alpha[r] = expf(m[r] - mn);
            lsum[r] = lsum[r] * alpha[r] + rs;
            m[r] = mn;
            p0[r] = e0;
            p1[r] = e1;
        }
#pragma unroll
        for (int db = 0; db < 8; db++)
#pragma unroll
            for (int r = 0; r < 4; r++) o[db][r] *= alpha[r];
#pragma unroll
        for (int r = 0; r < 4; r++) {
            plds[wid][lk * 4 + r][lq] = (short)f2bf(p0[r]);
            plds[wid][lk * 4 + r][16 + lq] = (short)f2bf(p1[r]);
        }
        short8 pa = *(const short8*)&plds[wid][lq][lk * 8];
#pragma unroll
        for (int db = 0; db < 8; db++) {
            short8 vf = *(const short8*)(vbase + (size_t)(db * 16 + lq) * KVL_ + kv0 + lk * 8);
            o[db] = __builtin_amdgcn_mfma_f32_16x16x32_bf16(pa, vf, o[db], 0, 0, 0);
        }
    };

    if (doc >= 1) {
        tile(RET_ * (doc - 1));
        tile(RET_ * (doc - 1) + 32);
    }
    for (int kv0 = IST_; kv0 < IST_ + qb + 16; kv0 += 32) tile(kv0);

    float inv[4];
#pragma unroll
    for (int r = 0; r < 4; r++) inv[r] = lsum[r] > 0.f ? 1.f / lsum[r] : 0.f;
    // write with the reference's head-interleaved reshape:
    // row = b*2048 + h*128 + (qg>>4), col = (qg&15)*128 + d
#pragma unroll
    for (int db = 0; db < 8; db++)
#pragma unroll
        for (int r = 0; r < 4; r++) {
            int qg = qb + lk * 4 + r;
            size_t row = (size_t)b * 2048 + h * 128 + (qg >> 4);
            size_t col = (size_t)(qg & 15) * 128 + db * 16 + lq;
            attnb[row * 2048 + col] = f2bf(o[db][r] * inv[r]);
        }
}

extern "C" void kernel_launch(void* const* d_in, const int* in_sizes, int n_in,
                              void* d_out, int out_size, void* d_ws, size_t ws_size,
                              hipStream_t stream) {
    const float* hidden = (const float*)d_in[0];
    const float* cosb = (const float*)d_in[1];
    const float* sinb = (const float*)d_in[2];
    const float* rk = (const float*)d_in[3];
    const float* rv = (const float*)d_in[4];
    const float* Wq = (const float*)d_in[5];
    const float* Wk = (const float*)d_in[6];
    const float* Wv = (const float*)d_in[7];
    const float* Wo = (const float*)d_in[8];
    float* out = (float*)d_out;

    char* ws = (char*)d_ws;
    unsigned short* hb = (unsigned short*)(ws + 0);              // 16,777,216
    unsigned short* wqT = (unsigned short*)(ws + 16777216);      // 8,388,608
    unsigned short* wkT = (unsigned short*)(ws + 25165824);      // 4,194,304
    unsigned short* wvT = (unsigned short*)(ws + 29360128);      // 4,194,304
    unsigned short* woT = (unsigned short*)(ws + 33554432);      // 8,388,608
    unsigned short* qraw = (unsigned short*)(ws + 41943040);     // 16,777,216
    unsigned short* kraw = (unsigned short*)(ws + 58720256);     // 8,388,608
    unsigned short* vraw = (unsigned short*)(ws + 67108864);     // 8,388,608
    unsigned short* qatt = (unsigned short*)(ws + 75497472);     // 16,777,216
    unsigned short* kallb = (unsigned short*)(ws + 92274688);    // 10,223,616
    unsigned short* vtb = (unsigned short*)(ws + 102498304);     // 10,223,616
    unsigned short* attnb = (unsigned short*)(ws + 112721920);   // 16,777,216

    cvt_f32_bf16<<<8192, 256, 0, stream>>>(hidden, hb, 2097152);
    transpose_cvt<<<dim3(64, 64), dim3(32, 8), 0, stream>>>(Wq, wqT, 2048, 2048);
    transpose_cvt<<<dim3(64, 32), dim3(32, 8), 0, stream>>>(Wk, wkT, 2048, 1024);
    transpose_cvt<<<dim3(64, 32), dim3(32, 8), 0, stream>>>(Wv, wvT, 2048, 1024);
    transpose_cvt<<<dim3(64, 64), dim3(32, 8), 0, stream>>>(Wo, woT, 2048, 2048);

    gemm_bt<unsigned short><<<dim3(32, 16), 256, 0, stream>>>(hb, wqT, qraw, 4096, 2048, 2048);
    gemm_bt<unsigned short><<<dim3(32, 8), 256, 0, stream>>>(hb, wkT, kraw, 4096, 1024, 2048);
    gemm_bt<unsigned short><<<dim3(32, 8), 256, 0, stream>>>(hb, wvT, vraw, 4096, 1024, 2048);

    rope_q_kernel<<<16384, 256, 0, stream>>>(qraw, cosb, sinb, qatt);
    rope_k_kernel<<<8192, 256, 0, stream>>>(kraw, cosb, sinb, kallb);
    scatter_v_kernel<<<dim3(4, 64, 16), dim3(32, 8), 0, stream>>>(vraw, vtb);
    scatter_rk_kernel<<<3584, 256, 0, stream>>>(rk, kallb);
    scatter_rv_kernel<<<dim3(4, 2, 112), dim3(32, 8), 0, stream>>>(rv, vtb);

    attn_kernel<<<dim3(32, 16, 2), 256, 0, stream>>>(qatt, kallb, vtb, attnb);

    gemm_bt<float><<<dim3(32, 16), 256, 0, stream>>>(attnb, woT, out, 4096, 2048, 2048);
}

// Round 4
// 368.586 us; speedup vs baseline: 2.1902x; 2.1902x over previous
//
#include <hip/hip_runtime.h>

#define B_ 2
#define S_ 2048
#define HID_ 2048
#define H_ 16
#define HKV_ 8
#define HD_ 128
#define NCH_ 7
#define RET_ 64
#define IST_ 448            // INPUT_START
#define KVL_ 2496           // KV_LEN
#define SCALE_ 0.08838834764831845f
#define SC2_ (0.08838834764831845f * 1.44269504088896340f)  // SCALE * log2(e)

typedef __attribute__((ext_vector_type(8))) short short8;
typedef __attribute__((ext_vector_type(4))) float f32x4;

static __device__ __forceinline__ unsigned short f2bf(float f) {
    unsigned u = __float_as_uint(f);
    unsigned r = (u + 0x7fffu + ((u >> 16) & 1u)) >> 16;
    return (unsigned short)r;
}
static __device__ __forceinline__ float bf2f(unsigned short x) {
    return __uint_as_float(((unsigned)x) << 16);
}

#define GLL16(gp, lp) __builtin_amdgcn_global_load_lds( \
    (__attribute__((address_space(1))) void*)(void*)(gp), \
    (__attribute__((address_space(3))) void*)(void*)(lp), 16, 0, 0)

// ---------------- elementwise f32 -> bf16 ----------------
__global__ __launch_bounds__(256) void cvt_f32_bf16(const float* __restrict__ x,
                                                    unsigned short* __restrict__ y, int n4) {
    int i = blockIdx.x * 256 + threadIdx.x;
    if (i >= n4) return;
    float4 v = ((const float4*)x)[i];
    ushort4 o;
    o.x = f2bf(v.x); o.y = f2bf(v.y); o.z = f2bf(v.z); o.w = f2bf(v.w);
    ((ushort4*)y)[i] = o;
}

// ---------------- W (K x N, f32) -> WT (N x K, bf16) ----------------
__global__ __launch_bounds__(256) void transpose_cvt(const float* __restrict__ W,
                                                     unsigned short* __restrict__ WT,
                                                     int K, int N) {
    __shared__ float t[32][33];
    const int k0 = blockIdx.x << 5, n0 = blockIdx.y << 5;
    const int tx = threadIdx.x, ty = threadIdx.y;
#pragma unroll
    for (int i = 0; i < 4; i++)
        t[ty + i * 8][tx] = W[(size_t)(k0 + ty + i * 8) * N + n0 + tx];
    __syncthreads();
#pragma unroll
    for (int i = 0; i < 4; i++)
        WT[(size_t)(n0 + ty + i * 8) * K + k0 + tx] = f2bf(t[tx][ty + i * 8]);
}

// ---------------- GEMM: C(MxN) = A(MxK,bf16) * BT(NxK,bf16)^T ----------------
static __device__ __forceinline__ void store_out(unsigned short* p, float v) { *p = f2bf(v); }
static __device__ __forceinline__ void store_out(float* p, float v) { *p = v; }

template <typename OT>
__global__ __launch_bounds__(256) void gemm_bt(const unsigned short* __restrict__ A,
                                               const unsigned short* __restrict__ BT,
                                               OT* __restrict__ C,
                                               int M, int N, int K) {
    __shared__ short As[4096];  // 128 x 32 bf16
    __shared__ short Bs[4096];
    const int tid = threadIdx.x;
    const int wid = tid >> 6, lane = tid & 63;
    const int lq = lane & 15, lk = lane >> 4;
    const int wr = wid >> 1, wc = wid & 1;
    const int bm = blockIdx.x, bn = blockIdx.y;
    f32x4 acc[4][4] = {};
    const int r0 = tid >> 2, kp0 = (tid & 3) * 8;
    const int c1 = tid + 256;
    const int r1 = c1 >> 2, kp1 = (c1 & 3) * 8;
    const size_t arow0 = (size_t)(bm * 128 + r0) * K;
    const size_t arow1 = (size_t)(bm * 128 + r1) * K;
    const size_t brow0 = (size_t)(bn * 128 + r0) * K;
    const size_t brow1 = (size_t)(bn * 128 + r1) * K;
    for (int k0 = 0; k0 < K; k0 += 32) {
        GLL16(A + arow0 + k0 + kp0, As + wid * 512);
        GLL16(A + arow1 + k0 + kp1, As + 2048 + wid * 512);
        GLL16(BT + brow0 + k0 + kp0, Bs + wid * 512);
        GLL16(BT + brow1 + k0 + kp1, Bs + 2048 + wid * 512);
        asm volatile("s_waitcnt vmcnt(0)" ::: "memory");
        __syncthreads();
        short8 af[4], bf[4];
#pragma unroll
        for (int i = 0; i < 4; i++)
            af[i] = *(const short8*)(As + (wr * 64 + i * 16 + lq) * 32 + lk * 8);
#pragma unroll
        for (int j = 0; j < 4; j++)
            bf[j] = *(const short8*)(Bs + (wc * 64 + j * 16 + lq) * 32 + lk * 8);
#pragma unroll
        for (int i = 0; i < 4; i++)
#pragma unroll
            for (int j = 0; j < 4; j++)
                acc[i][j] = __builtin_amdgcn_mfma_f32_16x16x32_bf16(af[i], bf[j], acc[i][j], 0, 0, 0);
        __syncthreads();
    }
#pragma unroll
    for (int i = 0; i < 4; i++)
#pragma unroll
        for (int j = 0; j < 4; j++)
#pragma unroll
            for (int r = 0; r < 4; r++) {
                size_t row = (size_t)bm * 128 + wr * 64 + i * 16 + lk * 4 + r;
                size_t col = (size_t)bn * 128 + wc * 64 + j * 16 + lq;
                store_out(&C[row * N + col], acc[i][j][r]);
            }
}

// ---------------- RoPE Q: qraw(B*S, H*HD) -> qatt(B,H,S,HD) ----------------
__global__ __launch_bounds__(256) void rope_q_kernel(const unsigned short* __restrict__ qraw,
                                                     const float* __restrict__ cosb,
                                                     const float* __restrict__ sinb,
                                                     unsigned short* __restrict__ qatt) {
    size_t idx = (size_t)blockIdx.x * 256 + threadIdx.x;  // B*S*H*64
    int d = idx & 63;
    int h = (idx >> 6) & 15;
    size_t bs = idx >> 10;
    size_t base = bs * 2048 + h * 128 + d;
    float x1 = bf2f(qraw[base]), x2 = bf2f(qraw[base + 64]);
    float c1 = cosb[bs * 128 + d], sn1 = sinb[bs * 128 + d];
    float c2 = cosb[bs * 128 + d + 64], sn2 = sinb[bs * 128 + d + 64];
    int b = (int)(bs >> 11), s = (int)(bs & 2047);
    size_t o = ((size_t)(b * H_ + h) * S_ + s) * HD_ + d;
    qatt[o] = f2bf(x1 * c1 - x2 * sn1);
    qatt[o + 64] = f2bf(x2 * c2 + x1 * sn2);
}

// ---------------- RoPE K: kraw(B*S, HKV*HD) -> kall(B,HKV,KVL,HD) at 448+s ----------------
__global__ __launch_bounds__(256) void rope_k_kernel(const unsigned short* __restrict__ kraw,
                                                     const float* __restrict__ cosb,
                                                     const float* __restrict__ sinb,
                                                     unsigned short* __restrict__ kall) {
    size_t idx = (size_t)blockIdx.x * 256 + threadIdx.x;  // B*S*HKV*64
    int d = idx & 63;
    int hk = (idx >> 6) & 7;
    size_t bs = idx >> 9;
    size_t base = bs * 1024 + hk * 128 + d;
    float x1 = bf2f(kraw[base]), x2 = bf2f(kraw[base + 64]);
    float c1 = cosb[bs * 128 + d], sn1 = sinb[bs * 128 + d];
    float c2 = cosb[bs * 128 + d + 64], sn2 = sinb[bs * 128 + d + 64];
    int b = (int)(bs >> 11), s = (int)(bs & 2047);
    size_t o = ((size_t)(b * HKV_ + hk) * KVL_ + IST_ + s) * HD_ + d;
    kall[o] = f2bf(x1 * c1 - x2 * sn1);
    kall[o + 64] = f2bf(x2 * c2 + x1 * sn2);
}

// ---------------- V self: vraw(B*S, HKV*HD) -> vt(B,HKV,HD,KVL) at col 448+s ----------------
__global__ void scatter_v_kernel(const unsigned short* __restrict__ vraw,
                                 unsigned short* __restrict__ vt) {
    __shared__ unsigned short t[32][33];
    const int bh = blockIdx.z;
    const int b = bh >> 3, hk = bh & 7;
    const int d0 = blockIdx.x << 5, s0 = blockIdx.y << 5;
    const int tx = threadIdx.x, ty = threadIdx.y;
#pragma unroll
    for (int i = 0; i < 4; i++)
        t[ty + i * 8][tx] = vraw[(size_t)(b * S_ + s0 + ty + i * 8) * 1024 + hk * 128 + d0 + tx];
    __syncthreads();
#pragma unroll
    for (int i = 0; i < 4; i++)
        vt[((size_t)(b * HKV_ + hk) * HD_ + d0 + ty + i * 8) * KVL_ + IST_ + s0 + tx] = t[tx][ty + i * 8];
}

// ---------------- retrieval K ----------------
__global__ __launch_bounds__(256) void scatter_rk_kernel(const float* __restrict__ rk,
                                                         unsigned short* __restrict__ kall) {
    size_t idx = (size_t)blockIdx.x * 256 + threadIdx.x;  // 14*8*64*128
    int d = idx & 127;
    int r = (idx >> 7) & 63;
    int hk = (idx >> 13) & 7;
    int bc = (int)(idx >> 16);
    int b = bc / NCH_, ch = bc % NCH_;
    kall[((size_t)(b * HKV_ + hk) * KVL_ + ch * RET_ + r) * HD_ + d] = f2bf(rk[idx]);
}

// ---------------- retrieval V (transpose) ----------------
__global__ void scatter_rv_kernel(const float* __restrict__ rv,
                                  unsigned short* __restrict__ vt) {
    __shared__ float t[32][33];
    const int z = blockIdx.z;
    const int bc = z >> 3, hk = z & 7;
    const int b = bc / NCH_, ch = bc % NCH_;
    const int d0 = blockIdx.x << 5, r0 = blockIdx.y << 5;
    const int tx = threadIdx.x, ty = threadIdx.y;
#pragma unroll
    for (int i = 0; i < 4; i++)
        t[ty + i * 8][tx] = rv[((size_t)(bc * HKV_ + hk) * RET_ + r0 + ty + i * 8) * HD_ + d0 + tx];
    __syncthreads();
#pragma unroll
    for (int i = 0; i < 4; i++)
        vt[((size_t)(b * HKV_ + hk) * HD_ + d0 + ty + i * 8) * KVL_ + ch * RET_ + r0 + tx] =
            f2bf(t[tx][ty + i * 8]);
}

// ---------------- flash attention ----------------
// grid (8, H, B), 512 threads = 8 waves.
// Block pairi processes q-halves pairi*128 and (15-pairi)*128 sequentially
// (complementary causal lengths -> uniform 35-36 KV tiles per block).
__global__ __launch_bounds__(512) void attn_kernel(const unsigned short* __restrict__ qatt,
                                                   const unsigned short* __restrict__ kall,
                                                   const unsigned short* __restrict__ vt,
                                                   unsigned short* __restrict__ attnb) {
    __shared__ short Ks[2][8192];   // [64 kv][128 d] bf16 (256B rows), 16B-chunk swizzled
    __shared__ short Vs[2][8192];   // [128 d][64 kv] bf16 (128B rows), swizzled
    __shared__ short Ps[8][1024];   // per-wave [16 q][64 kv] bf16 (128B rows), swizzled
    const int tid = threadIdx.x;
    const int wid = tid >> 6, lane = tid & 63;
    const int lq = lane & 15, lk = lane >> 4;
    const int pairi = blockIdx.x;
    const int h = blockIdx.y, b = blockIdx.z, hk = h >> 1;
    const unsigned short* kbase = kall + (size_t)(b * HKV_ + hk) * KVL_ * HD_;
    const unsigned short* vbase = vt + (size_t)(b * HKV_ + hk) * HD_ * KVL_;

    // per-thread staging constants (2 rounds of 8KB per 16KB tile)
    int krow[2], koffe[2];
    const unsigned short* vrp[2];
#pragma unroll
    for (int p = 0; p < 2; p++) {
        int o = p * 8192 + wid * 1024 + lane * 16;   // byte offset in tile
        int r = o >> 8;                               // K row (256B rows)
        int c = lane & 15;                            // 16B chunk in K row
        krow[p] = r;
        koffe[p] = ((c ^ (r & 7)) << 3);              // element offset (swizzled source)
        int rv = o >> 7;                              // V row (128B rows)
        int cv = lane & 7;
        vrp[p] = vbase + (size_t)rv * KVL_ + ((cv ^ (rv & 7)) << 3);
    }
    short* psw = &Ps[wid][0];

    for (int hh = 0; hh < 2; hh++) {
        const int qb0 = (hh == 0 ? pairi : 15 - pairi) * 128;
        const int qbw = qb0 + wid * 16;
        const int doc = qb0 >> 8;
        const unsigned short* qptr = qatt + ((size_t)(b * H_ + h) * S_ + qbw + lq) * HD_;
        short8 qf[4];
#pragma unroll
        for (int d = 0; d < 4; d++) qf[d] = *(const short8*)(qptr + d * 32 + lk * 8);
        f32x4 o[8] = {};
        float m[4] = {-3e38f, -3e38f, -3e38f, -3e38f};
        float lsum[4] = {0.f, 0.f, 0.f, 0.f};

        const int nt = (doc >= 1 ? 1 : 0) + (qb0 + 128) / 64;
        auto kvof = [&](int t) {
            return (doc >= 1) ? (t == 0 ? RET_ * (doc - 1) : IST_ + (t - 1) * 64)
                              : IST_ + t * 64;
        };
        auto stage = [&](int buf, int kv0) {
#pragma unroll
            for (int p = 0; p < 2; p++) {
                GLL16(kbase + (size_t)(kv0 + krow[p]) * HD_ + koffe[p],
                      &Ks[buf][p * 4096 + wid * 512]);
                GLL16(vrp[p] + kv0, &Vs[buf][p * 4096 + wid * 512]);
            }
        };

        stage(0, kvof(0));
        asm volatile("s_waitcnt vmcnt(0)" ::: "memory");
        __syncthreads();
        int cur = 0;
        for (int t = 0; t < nt; t++) {
            if (t + 1 < nt) stage(cur ^ 1, kvof(t + 1));
            const int kv0 = kvof(t);
            const bool isret = (doc >= 1 && t == 0);
            if (isret || kv0 <= qbw + 15 + IST_) {
                const char* kb = (const char*)&Ks[cur][0];
                const char* vb = (const char*)&Vs[cur][0];
                f32x4 sa[4] = {};
#pragma unroll
                for (int d = 0; d < 4; d++) {
#pragma unroll
                    for (int j = 0; j < 4; j++) {
                        short8 kf = *(const short8*)(kb + ((j * 16 + lq) * 256 +
                                                           (((d * 4 + lk) ^ (lq & 7)) << 4)));
                        sa[j] = __builtin_amdgcn_mfma_f32_16x16x32_bf16(qf[d], kf, sa[j], 0, 0, 0);
                    }
                }
                float alpha[4];
#pragma unroll
                for (int r = 0; r < 4; r++) {
                    const int qg = qbw + lk * 4 + r;
                    float sc[4];
                    float mxl = -3e38f;
#pragma unroll
                    for (int j = 0; j < 4; j++) {
                        int kg = kv0 + j * 16 + lq;
                        bool v = isret || (kg > IST_ && kg <= qg + IST_);
                        sc[j] = v ? sa[j][r] * SC2_ : -3e38f;
                        mxl = fmaxf(mxl, sc[j]);
                    }
                    mxl = fmaxf(mxl, __shfl_xor(mxl, 1));
                    mxl = fmaxf(mxl, __shfl_xor(mxl, 2));
                    mxl = fmaxf(mxl, __shfl_xor(mxl, 4));
                    mxl = fmaxf(mxl, __shfl_xor(mxl, 8));
                    float mn = fmaxf(fmaxf(m[r], mxl), -1e30f);
                    float rs = 0.f;
                    const int prow = lk * 4 + r;
#pragma unroll
                    for (int j = 0; j < 4; j++) {
                        float p = __builtin_amdgcn_exp2f(sc[j] - mn);
                        rs += p;
                        *(short*)((char*)psw + ((prow * 128 + ((j * 16 + lq) << 1)) ^
                                                ((prow & 7) << 4))) = (short)f2bf(p);
                    }
                    rs += __shfl_xor(rs, 1);
                    rs += __shfl_xor(rs, 2);
                    rs += __shfl_xor(rs, 4);
                    rs += __shfl_xor(rs, 8);
                    alpha[r] = __builtin_amdgcn_exp2f(m[r] - mn);
                    m[r] = mn;
                    lsum[r] = lsum[r] * alpha[r] + rs;
                }
#pragma unroll
                for (int db = 0; db < 8; db++)
#pragma unroll
                    for (int r = 0; r < 4; r++) o[db][r] *= alpha[r];
#pragma unroll
                for (int ks = 0; ks < 2; ks++) {
                    short8 pa = *(const short8*)((const char*)psw +
                                                 (lq * 128 + (((ks * 4 + lk) ^ (lq & 7)) << 4)));
#pragma unroll
                    for (int db = 0; db < 8; db++) {
                        short8 vf = *(const short8*)(vb + ((db * 16 + lq) * 128 +
                                                           (((ks * 4 + lk) ^ (lq & 7)) << 4)));
                        o[db] = __builtin_amdgcn_mfma_f32_16x16x32_bf16(pa, vf, o[db], 0, 0, 0);
                    }
                }
            }
            if (t + 1 < nt) asm volatile("s_waitcnt vmcnt(0)" ::: "memory");
            __syncthreads();
            cur ^= 1;
        }

        float inv[4];
#pragma unroll
        for (int r = 0; r < 4; r++) inv[r] = lsum[r] > 0.f ? 1.f / lsum[r] : 0.f;
        // reference reshape (B,H,S,HD)->(B,S,H*HD): row = b*2048+h*128+(qg>>4), col=(qg&15)*128+d
#pragma unroll
        for (int db = 0; db < 8; db++)
#pragma unroll
            for (int r = 0; r < 4; r++) {
                int qg = qbw + lk * 4 + r;
                size_t row = (size_t)b * 2048 + h * 128 + (qg >> 4);
                size_t col = (size_t)(qg & 15) * 128 + db * 16 + lq;
                attnb[row * 2048 + col] = f2bf(o[db][r] * inv[r]);
            }
    }
}

extern "C" void kernel_launch(void* const* d_in, const int* in_sizes, int n_in,
                              void* d_out, int out_size, void* d_ws, size_t ws_size,
                              hipStream_t stream) {
    const float* hidden = (const float*)d_in[0];
    const float* cosb = (const float*)d_in[1];
    const float* sinb = (const float*)d_in[2];
    const float* rk = (const float*)d_in[3];
    const float* rv = (const float*)d_in[4];
    const float* Wq = (const float*)d_in[5];
    const float* Wk = (const float*)d_in[6];
    const float* Wv = (const float*)d_in[7];
    const float* Wo = (const float*)d_in[8];
    float* out = (float*)d_out;

    char* ws = (char*)d_ws;
    unsigned short* hb = (unsigned short*)(ws + 0);
    unsigned short* wqT = (unsigned short*)(ws + 16777216);
    unsigned short* wkT = (unsigned short*)(ws + 25165824);
    unsigned short* wvT = (unsigned short*)(ws + 29360128);
    unsigned short* woT = (unsigned short*)(ws + 33554432);
    unsigned short* qraw = (unsigned short*)(ws + 41943040);
    unsigned short* kraw = (unsigned short*)(ws + 58720256);
    unsigned short* vraw = (unsigned short*)(ws + 67108864);
    unsigned short* qatt = (unsigned short*)(ws + 75497472);
    unsigned short* kallb = (unsigned short*)(ws + 92274688);
    unsigned short* vtb = (unsigned short*)(ws + 102498304);
    unsigned short* attnb = (unsigned short*)(ws + 112721920);

    cvt_f32_bf16<<<8192, 256, 0, stream>>>(hidden, hb, 2097152);
    transpose_cvt<<<dim3(64, 64), dim3(32, 8), 0, stream>>>(Wq, wqT, 2048, 2048);
    transpose_cvt<<<dim3(64, 32), dim3(32, 8), 0, stream>>>(Wk, wkT, 2048, 1024);
    transpose_cvt<<<dim3(64, 32), dim3(32, 8), 0, stream>>>(Wv, wvT, 2048, 1024);
    transpose_cvt<<<dim3(64, 64), dim3(32, 8), 0, stream>>>(Wo, woT, 2048, 2048);

    gemm_bt<unsigned short><<<dim3(32, 16), 256, 0, stream>>>(hb, wqT, qraw, 4096, 2048, 2048);
    gemm_bt<unsigned short><<<dim3(32, 8), 256, 0, stream>>>(hb, wkT, kraw, 4096, 1024, 2048);
    gemm_bt<unsigned short><<<dim3(32, 8), 256, 0, stream>>>(hb, wvT, vraw, 4096, 1024, 2048);

    rope_q_kernel<<<16384, 256, 0, stream>>>(qraw, cosb, sinb, qatt);
    rope_k_kernel<<<8192, 256, 0, stream>>>(kraw, cosb, sinb, kallb);
    scatter_v_kernel<<<dim3(4, 64, 16), dim3(32, 8), 0, stream>>>(vraw, vtb);
    scatter_rk_kernel<<<3584, 256, 0, stream>>>(rk, kallb);
    scatter_rv_kernel<<<dim3(4, 2, 112), dim3(32, 8), 0, stream>>>(rv, vtb);

    attn_kernel<<<dim3(8, 16, 2), 512, 0, stream>>>(qatt, kallb, vtb, attnb);

    gemm_bt<float><<<dim3(32, 16), 256, 0, stream>>>(attnb, woT, out, 4096, 2048, 2048);
}